// Round 2
// baseline (121.560 us; speedup 1.0000x reference)
//
#include <hip/hip_runtime.h>
#include <math.h>

// ---------------------------------------------------------------------------
// HQNN via trig-polynomial compression.
//
// For each hybrid layer, the 4-qubit circuit's Z-expvals as a function of the
// 4 input angles h are EXACTLY:
//   E_w(h) = sum_{g in {0,1,2}^4} D_w[g] * prod_w f(g_w, h_w),
//   f(0,h)=1, f(1,h)=cos h, f(2,h)=sin h
// (embedding amplitudes are quadratic in cos/sin(h/2) per wire; the entangler
// is batch-constant). setup_D computes the 3 x 81 x 4 coefficient tensor by
// gate-simulating the circuit on an 81-point grid h_w in {0, pi/2, pi} and
// applying the 3x3 inverse Vandermonde along each wire dimension.
//
// Main kernel per layer: dense+tanh -> 4x sincos -> 8 muls -> 81*(mul+4fma).
// ---------------------------------------------------------------------------

__device__ __forceinline__ float fast_tanh(float x) {
    float u = __expf(2.0f * x);
    return 1.0f - 2.0f * __builtin_amdgcn_rcpf(u + 1.0f);
}

// ------------------------- setup: gate simulation --------------------------

__device__ __forceinline__ void s_apply_rx(float2 st[16], int w, float c, float s) {
    const int bit = 1 << w;
#pragma unroll
    for (int b = 0; b < 16; ++b) {
        if (!(b & bit)) {
            float2 a0 = st[b];
            float2 a1 = st[b | bit];
            st[b].x       = fmaf(c, a0.x,  s * a1.y);
            st[b].y       = fmaf(c, a0.y, -s * a1.x);
            st[b | bit].x = fmaf(c, a1.x,  s * a0.y);
            st[b | bit].y = fmaf(c, a1.y, -s * a0.x);
        }
    }
}

__device__ __forceinline__ void s_apply_cnot(float2 st[16], int c, int t) {
    const int cb = 1 << c, tb = 1 << t;
#pragma unroll
    for (int b = 0; b < 16; ++b) {
        if ((b & cb) && !(b & tb)) {
            float2 tmp = st[b];
            st[b] = st[b | tb];
            st[b | tb] = tmp;
        }
    }
}

// One block of 128 threads. D layout: D[(layer*81 + t)*4 + w], t = base-3
// encoding g0 + 3*g1 + 9*g2 + 27*g3.
__global__ void setup_D(const float* __restrict__ theta, float* __restrict__ D) {
    __shared__ float bufA[81 * 4];
    __shared__ float bufB[81 * 4];
    const int t = threadIdx.x;

    for (int layer = 0; layer < 3; ++layer) {
        if (t < 81) {
            const int g0 = t % 3, g1 = (t / 3) % 3, g2 = (t / 9) % 3, g3 = t / 27;
            const float H[3] = {0.0f, 1.5707963267948966f, 3.14159265358979323f};
            float h[4] = {H[g0], H[g1], H[g2], H[g3]};

            float2 st[16];
#pragma unroll
            for (int b = 0; b < 16; ++b) st[b] = make_float2(0.0f, 0.0f);
            st[0] = make_float2(1.0f, 0.0f);

            for (int w = 0; w < 4; ++w)
                s_apply_rx(st, w, cosf(0.5f * h[w]), sinf(0.5f * h[w]));
            for (int l = 0; l < 2; ++l) {
                for (int w = 0; w < 4; ++w) {
                    float th = 0.5f * theta[layer * 8 + l * 4 + w];
                    s_apply_rx(st, w, cosf(th), sinf(th));
                }
                for (int w = 0; w < 4; ++w)
                    s_apply_cnot(st, w, (w + 1) & 3);
            }
            float pr[16], total = 0.0f;
#pragma unroll
            for (int b = 0; b < 16; ++b) {
                pr[b] = st[b].x * st[b].x + st[b].y * st[b].y;
                total += pr[b];
            }
            for (int w = 0; w < 4; ++w) {
                float s1 = 0.0f;
#pragma unroll
                for (int b = 0; b < 16; ++b)
                    if ((b >> w) & 1) s1 += pr[b];
                bufA[t * 4 + w] = total - 2.0f * s1;
            }
        }
        __syncthreads();

        // inverse Vandermonde along each wire dim:
        // a0 = (y0+y2)/2 ; a1(cos) = (y0-y2)/2 ; a2(sin) = y1 - (y0+y2)/2
        float* src = bufA;
        float* dst = bufB;
        int stride = 1;
        for (int d = 0; d < 4; ++d) {
            if (t < 81) {
                int digit = (t / stride) % 3;
                int base = t - digit * stride;
                for (int c = 0; c < 4; ++c) {
                    float y0 = src[(base + 0 * stride) * 4 + c];
                    float y1 = src[(base + 1 * stride) * 4 + c];
                    float y2 = src[(base + 2 * stride) * 4 + c];
                    float m = 0.5f * (y0 + y2);
                    float a = (digit == 0) ? m : (digit == 1) ? 0.5f * (y0 - y2) : (y1 - m);
                    dst[t * 4 + c] = a;
                }
            }
            __syncthreads();
            float* tmp = src; src = dst; dst = tmp;
            stride *= 3;
        }
        if (t < 81) {
            for (int c = 0; c < 4; ++c)
                D[(layer * 81 + t) * 4 + c] = src[t * 4 + c];
        }
        __syncthreads();
    }
}

// ------------------------------ main kernel --------------------------------

__global__ __launch_bounds__(256, 4)
void hqnn_kernel(const float4* __restrict__ x4,
                 const float4* __restrict__ D4,   // [3*81] float4 of coefs
                 const float* __restrict__ W0, const float* __restrict__ b0,
                 const float* __restrict__ W1, const float* __restrict__ b1,
                 const float* __restrict__ W2, const float* __restrict__ b2,
                 float4* __restrict__ out, int B) {
    int i = blockIdx.x * blockDim.x + threadIdx.x;
    if (i >= B) return;

    float4 v0 = x4[i * 4 + 0];
    float4 v1 = x4[i * 4 + 1];
    float4 v2 = x4[i * 4 + 2];
    float4 v3 = x4[i * 4 + 3];
    float xr[16] = {v0.x, v0.y, v0.z, v0.w, v1.x, v1.y, v1.z, v1.w,
                    v2.x, v2.y, v2.z, v2.w, v3.x, v3.y, v3.z, v3.w};

    float h[4];
#pragma unroll
    for (int j = 0; j < 4; ++j) {
        float acc = b0[j];
#pragma unroll
        for (int k = 0; k < 16; ++k) acc = fmaf(xr[k], W0[k * 4 + j], acc);
        h[j] = fast_tanh(acc);
    }

#pragma unroll
    for (int layer = 0; layer < 3; ++layer) {
        if (layer > 0) {
            const float* W = (layer == 1) ? W1 : W2;
            const float* b = (layer == 1) ? b1 : b2;
            float g[4];
#pragma unroll
            for (int j = 0; j < 4; ++j) {
                float acc = b[j];
#pragma unroll
                for (int k = 0; k < 4; ++k) acc = fmaf(h[k], W[k * 4 + j], acc);
                g[j] = fast_tanh(acc);
            }
#pragma unroll
            for (int j = 0; j < 4; ++j) h[j] = g[j];
        }

        // full-angle sincos per wire (h in (-1,1): native trig is accurate)
        float c0 = __cosf(h[0]), s0 = __sinf(h[0]);
        float c1 = __cosf(h[1]), s1 = __sinf(h[1]);
        float c2 = __cosf(h[2]), s2 = __sinf(h[2]);
        float c3 = __cosf(h[3]), s3 = __sinf(h[3]);

        // product tables, index i = g1*3 + g0 with f = {1, c, s}
        float p01[9] = {1.0f, c0, s0, c1, c1 * c0, c1 * s0, s1, s1 * c0, s1 * s0};
        float p23[9] = {1.0f, c2, s2, c3, c3 * c2, c3 * s2, s3, s3 * c2, s3 * s2};

        float E0 = 0.0f, E1 = 0.0f, E2 = 0.0f, E3 = 0.0f;
#pragma unroll
        for (int j = 0; j < 9; ++j) {
#pragma unroll
            for (int ii = 0; ii < 9; ++ii) {
                float T = p01[ii] * p23[j];
                float4 d = D4[layer * 81 + j * 9 + ii];  // wave-uniform
                E0 = fmaf(d.x, T, E0);
                E1 = fmaf(d.y, T, E1);
                E2 = fmaf(d.z, T, E2);
                E3 = fmaf(d.w, T, E3);
            }
        }
        h[0] = E0; h[1] = E1; h[2] = E2; h[3] = E3;
    }

    out[i] = make_float4(h[0], h[1], h[2], h[3]);
}

extern "C" void kernel_launch(void* const* d_in, const int* in_sizes, int n_in,
                              void* d_out, int out_size, void* d_ws, size_t ws_size,
                              hipStream_t stream) {
    const float* x  = (const float*)d_in[0];
    const float* th = (const float*)d_in[1];   // (3,2,4) = 24 floats
    const float* W0 = (const float*)d_in[2];
    const float* b0 = (const float*)d_in[3];
    const float* W1 = (const float*)d_in[4];
    const float* b1 = (const float*)d_in[5];
    const float* W2 = (const float*)d_in[6];
    const float* b2 = (const float*)d_in[7];
    float* out = (float*)d_out;
    float* D   = (float*)d_ws;                 // 3*81*4 floats = 3888 B

    int B = in_sizes[0] / 16;

    hipLaunchKernelGGL(setup_D, dim3(1), dim3(128), 0, stream, th, D);

    int block = 256;
    int grid = (B + block - 1) / block;
    hipLaunchKernelGGL(hqnn_kernel, dim3(grid), dim3(block), 0, stream,
                       (const float4*)x, (const float4*)D,
                       W0, b0, W1, b1, W2, b2,
                       (float4*)out, B);
}

// Round 3
// 103.277 us; speedup vs baseline: 1.1770x; 1.1770x over previous
//
#include <hip/hip_runtime.h>
#include <math.h>

// ---------------------------------------------------------------------------
// HQNN via trig-polynomial compression.
//   E_w(h) = sum_{g in {0,1,2}^4} D_w[g] * prod_w f(g_w, h_w),
//   f(0,h)=1, f(1,h)=cos h, f(2,h)=sin h   (exact; entangler is batch-const)
// setup_D: one block PER LAYER (3 blocks) gate-sims an 81-point grid and
// applies the 3x3 inverse Vandermonde per wire dim.
// main kernel: 2 rows/thread, packed-f32 (v_pk_fma) contraction, wave-uniform
// float4 coefficient loads.
// ---------------------------------------------------------------------------

typedef float v2f __attribute__((ext_vector_type(2)));

__device__ __forceinline__ float fast_tanh(float x) {
    float u = __expf(2.0f * x);
    return 1.0f - 2.0f * __builtin_amdgcn_rcpf(u + 1.0f);
}

// ------------------------- setup: gate simulation --------------------------

__device__ __forceinline__ void s_apply_rx(float2 st[16], int w, float c, float s) {
    const int bit = 1 << w;
#pragma unroll
    for (int b = 0; b < 16; ++b) {
        if (!(b & bit)) {
            float2 a0 = st[b];
            float2 a1 = st[b | bit];
            st[b].x       = fmaf(c, a0.x,  s * a1.y);
            st[b].y       = fmaf(c, a0.y, -s * a1.x);
            st[b | bit].x = fmaf(c, a1.x,  s * a0.y);
            st[b | bit].y = fmaf(c, a1.y, -s * a0.x);
        }
    }
}

__device__ __forceinline__ void s_apply_cnot(float2 st[16], int c, int t) {
    const int cb = 1 << c, tb = 1 << t;
#pragma unroll
    for (int b = 0; b < 16; ++b) {
        if ((b & cb) && !(b & tb)) {
            float2 tmp = st[b];
            st[b] = st[b | tb];
            st[b | tb] = tmp;
        }
    }
}

// grid = 3 blocks (one per layer), 128 threads each.
// D layout: D[(layer*81 + t)*4 + w], t = g0 + 3*g1 + 9*g2 + 27*g3.
__global__ void setup_D(const float* __restrict__ theta, float* __restrict__ D) {
    __shared__ float bufA[81 * 4];
    __shared__ float bufB[81 * 4];
    const int t = threadIdx.x;
    const int layer = blockIdx.x;

    if (t < 81) {
        const int g0 = t % 3, g1 = (t / 3) % 3, g2 = (t / 9) % 3, g3 = t / 27;
        const float H[3] = {0.0f, 1.5707963267948966f, 3.14159265358979323f};
        float h[4] = {H[g0], H[g1], H[g2], H[g3]};

        float2 st[16];
#pragma unroll
        for (int b = 0; b < 16; ++b) st[b] = make_float2(0.0f, 0.0f);
        st[0] = make_float2(1.0f, 0.0f);

        for (int w = 0; w < 4; ++w)
            s_apply_rx(st, w, __cosf(0.5f * h[w]), __sinf(0.5f * h[w]));
        for (int l = 0; l < 2; ++l) {
            for (int w = 0; w < 4; ++w) {
                float th = 0.5f * theta[layer * 8 + l * 4 + w];
                s_apply_rx(st, w, __cosf(th), __sinf(th));
            }
            for (int w = 0; w < 4; ++w)
                s_apply_cnot(st, w, (w + 1) & 3);
        }
        float pr[16], total = 0.0f;
#pragma unroll
        for (int b = 0; b < 16; ++b) {
            pr[b] = st[b].x * st[b].x + st[b].y * st[b].y;
            total += pr[b];
        }
        for (int w = 0; w < 4; ++w) {
            float s1 = 0.0f;
#pragma unroll
            for (int b = 0; b < 16; ++b)
                if ((b >> w) & 1) s1 += pr[b];
            bufA[t * 4 + w] = total - 2.0f * s1;
        }
    }
    __syncthreads();

    // inverse Vandermonde per wire dim:
    // a0 = (y0+y2)/2 ; a_cos = (y0-y2)/2 ; a_sin = y1 - (y0+y2)/2
    float* src = bufA;
    float* dst = bufB;
    int stride = 1;
    for (int d = 0; d < 4; ++d) {
        if (t < 81) {
            int digit = (t / stride) % 3;
            int base = t - digit * stride;
            for (int c = 0; c < 4; ++c) {
                float y0 = src[(base + 0 * stride) * 4 + c];
                float y1 = src[(base + 1 * stride) * 4 + c];
                float y2 = src[(base + 2 * stride) * 4 + c];
                float m = 0.5f * (y0 + y2);
                float a = (digit == 0) ? m : (digit == 1) ? 0.5f * (y0 - y2) : (y1 - m);
                dst[t * 4 + c] = a;
            }
        }
        __syncthreads();
        float* tmp = src; src = dst; dst = tmp;
        stride *= 3;
    }
    if (t < 81) {
        for (int c = 0; c < 4; ++c)
            D[(layer * 81 + t) * 4 + c] = src[t * 4 + c];
    }
}

// ------------------------------ main kernel --------------------------------

__device__ __forceinline__ void dense_tanh4(float h[4], const float* __restrict__ W,
                                            const float* __restrict__ b) {
    float g[4];
#pragma unroll
    for (int j = 0; j < 4; ++j) {
        float acc = b[j];
#pragma unroll
        for (int k = 0; k < 4; ++k) acc = fmaf(h[k], W[k * 4 + j], acc);
        g[j] = fast_tanh(acc);
    }
#pragma unroll
    for (int j = 0; j < 4; ++j) h[j] = g[j];
}

__device__ __forceinline__ void dense0_tanh(const float4* __restrict__ x4, int row,
                                            const float* __restrict__ W0,
                                            const float* __restrict__ b0, float h[4]) {
    float4 v0 = x4[row * 4 + 0];
    float4 v1 = x4[row * 4 + 1];
    float4 v2 = x4[row * 4 + 2];
    float4 v3 = x4[row * 4 + 3];
    float xr[16] = {v0.x, v0.y, v0.z, v0.w, v1.x, v1.y, v1.z, v1.w,
                    v2.x, v2.y, v2.z, v2.w, v3.x, v3.y, v3.z, v3.w};
#pragma unroll
    for (int j = 0; j < 4; ++j) {
        float acc = b0[j];
#pragma unroll
        for (int k = 0; k < 16; ++k) acc = fmaf(xr[k], W0[k * 4 + j], acc);
        h[j] = fast_tanh(acc);
    }
}

__device__ __forceinline__ void build_tables(const float h[4], float p01[9], float p23[9]) {
    float c0 = __cosf(h[0]), s0 = __sinf(h[0]);
    float c1 = __cosf(h[1]), s1 = __sinf(h[1]);
    float c2 = __cosf(h[2]), s2 = __sinf(h[2]);
    float c3 = __cosf(h[3]), s3 = __sinf(h[3]);
    p01[0] = 1.0f; p01[1] = c0;      p01[2] = s0;
    p01[3] = c1;   p01[4] = c1 * c0; p01[5] = c1 * s0;
    p01[6] = s1;   p01[7] = s1 * c0; p01[8] = s1 * s0;
    p23[0] = 1.0f; p23[1] = c2;      p23[2] = s2;
    p23[3] = c3;   p23[4] = c3 * c2; p23[5] = c3 * s2;
    p23[6] = s3;   p23[7] = s3 * c2; p23[8] = s3 * s2;
}

__global__ __launch_bounds__(256, 4)
void hqnn_kernel(const float4* __restrict__ x4,
                 const float4* __restrict__ D4,   // [3*81] float4 of coefs
                 const float* __restrict__ W0, const float* __restrict__ b0,
                 const float* __restrict__ W1, const float* __restrict__ b1,
                 const float* __restrict__ W2, const float* __restrict__ b2,
                 float4* __restrict__ out, int Bhalf) {
    int i = blockIdx.x * blockDim.x + threadIdx.x;
    if (i >= Bhalf) return;
    const int ra = i, rb = i + Bhalf;   // 2 rows per thread, both coalesced

    float ha[4], hb[4];
    dense0_tanh(x4, ra, W0, b0, ha);
    dense0_tanh(x4, rb, W0, b0, hb);

#pragma unroll
    for (int layer = 0; layer < 3; ++layer) {
        if (layer > 0) {
            const float* W = (layer == 1) ? W1 : W2;
            const float* b = (layer == 1) ? b1 : b2;
            dense_tanh4(ha, W, b);
            dense_tanh4(hb, W, b);
        }

        float p01a[9], p23a[9], p01b[9], p23b[9];
        build_tables(ha, p01a, p23a);
        build_tables(hb, p01b, p23b);

        v2f Ea01 = {0.0f, 0.0f}, Ea23 = {0.0f, 0.0f};
        v2f Eb01 = {0.0f, 0.0f}, Eb23 = {0.0f, 0.0f};
#pragma unroll
        for (int j = 0; j < 9; ++j) {
#pragma unroll
            for (int ii = 0; ii < 9; ++ii) {
                float4 d = D4[layer * 81 + j * 9 + ii];  // wave-uniform
                v2f d01 = {d.x, d.y};
                v2f d23 = {d.z, d.w};
                float Ta = p01a[ii] * p23a[j];
                float Tb = p01b[ii] * p23b[j];
                v2f Tva = {Ta, Ta};
                v2f Tvb = {Tb, Tb};
                Ea01 = d01 * Tva + Ea01;   // v_pk_fma_f32
                Ea23 = d23 * Tva + Ea23;
                Eb01 = d01 * Tvb + Eb01;
                Eb23 = d23 * Tvb + Eb23;
            }
        }
        ha[0] = Ea01.x; ha[1] = Ea01.y; ha[2] = Ea23.x; ha[3] = Ea23.y;
        hb[0] = Eb01.x; hb[1] = Eb01.y; hb[2] = Eb23.x; hb[3] = Eb23.y;
    }

    out[ra] = make_float4(ha[0], ha[1], ha[2], ha[3]);
    out[rb] = make_float4(hb[0], hb[1], hb[2], hb[3]);
}

extern "C" void kernel_launch(void* const* d_in, const int* in_sizes, int n_in,
                              void* d_out, int out_size, void* d_ws, size_t ws_size,
                              hipStream_t stream) {
    const float* x  = (const float*)d_in[0];
    const float* th = (const float*)d_in[1];   // (3,2,4) = 24 floats
    const float* W0 = (const float*)d_in[2];
    const float* b0 = (const float*)d_in[3];
    const float* W1 = (const float*)d_in[4];
    const float* b1 = (const float*)d_in[5];
    const float* W2 = (const float*)d_in[6];
    const float* b2 = (const float*)d_in[7];
    float* out = (float*)d_out;
    float* D   = (float*)d_ws;                 // 3*81*4 floats = 3888 B

    int B = in_sizes[0] / 16;
    int Bhalf = B / 2;

    hipLaunchKernelGGL(setup_D, dim3(3), dim3(128), 0, stream, th, D);

    int block = 256;
    int grid = (Bhalf + block - 1) / block;
    hipLaunchKernelGGL(hqnn_kernel, dim3(grid), dim3(block), 0, stream,
                       (const float4*)x, (const float4*)D,
                       W0, b0, W1, b1, W2, b2,
                       (float4*)out, Bhalf);
}